// Round 5
// baseline (985.031 us; speedup 1.0000x reference)
//
#include <hip/hip_runtime.h>
#include <hip/hip_bf16.h>

#ifndef BN_EPS
#define BN_EPS 1e-5f
#endif

// ---------------------------------------------------------------------------
// N=100000, C=64, E=1600000.
// R16: single persistent kernel, 3 grid-wide spin barriers.
//   R15 post-mortem: every kernel < 43us; residual ~80us = ~10us/dispatch
//   boundary. Fuse the whole pipeline: P1 bin -> bar -> P2 csr+conv -> bar
//   -> P3 agg + in-register o=row@W (shfl-broadcast) + fused BN stats ->
//   bar -> P4 bnprep + o recompute (own-L2 rows) + store. gemm1 deleted.
//   Grid 1280 = 5 blk/CU x 256 CU, __launch_bounds__(256,5) (VGPR<=102),
//   LDS union 28800B (5x28800=144K<=160K) -> full co-residency guaranteed;
//   barriers are fence/atomic-arrive/spin/fence at agent scope (the
//   cooperative grid.sync pattern). Cross-XCD partial-line binned writes
//   already exercised at R15's k_pre->k_csr boundary.
// 2 dispatches: memset(bar+cnt2), k_mega.
// bias cancels inside BatchNorm, skipped.
// ---------------------------------------------------------------------------

#define CAP2 3072   // per-sub-bucket slack capacity (mean 2048, sigma 45)
#define CHUNK 3072  // P1 edges per LDS chunk

__device__ __forceinline__ unsigned short f2bf(float f) {
    unsigned u = __float_as_uint(f);
    u += 0x7FFF + ((u >> 16) & 1);  // round-to-nearest-even
    return (unsigned short)(u >> 16);
}
__device__ __forceinline__ float bf2f(unsigned v) {
    return __uint_as_float(v << 16);
}

// Grid barrier: release-fence, arrive, spin to target, acquire-fence.
__device__ __forceinline__ void gbar(int* bar, int target) {
    __syncthreads();
    if (threadIdx.x == 0) {
        __threadfence();  // writeback this XCD's L2 (release)
        __hip_atomic_fetch_add(bar, 1, __ATOMIC_ACQ_REL, __HIP_MEMORY_SCOPE_AGENT);
        while (__hip_atomic_load(bar, __ATOMIC_ACQUIRE, __HIP_MEMORY_SCOPE_AGENT) < target)
            __builtin_amdgcn_s_sleep(16);
        __threadfence();  // invalidate stale lines (acquire)
    }
    __syncthreads();
}

__global__ __launch_bounds__(256, 5) void k_mega(
        const int* __restrict__ src, const int* __restrict__ dst,
        const float* __restrict__ x, const float* __restrict__ W,
        const float* __restrict__ gamma, const float* __restrict__ beta,
        float* __restrict__ out,
        int* bar, int* cnt2, float* stats,
        int* __restrict__ deg, float* __restrict__ dinv,
        int* __restrict__ offs, unsigned short* __restrict__ xb2,
        unsigned* __restrict__ aggb32, unsigned* __restrict__ binned,
        int N, int E, int SUB, float invN) {
    __shared__ __align__(16) char smem[28800];
    const int tid = threadIdx.x;
    const int bid = blockIdx.x;
    const int G = gridDim.x;

    // P0 (block 0): zero stats + the xb2 zero row (gather target for tails).
    if (bid == 0) {
        if (tid < 128) stats[tid] = 0.f;
        if (tid < 32) ((unsigned*)(xb2 + (size_t)N * 64))[tid] = 0u;
    }

    // ---- P1: direct 782-bucket binning (cnt2 pre-zeroed by memset) ----
    {
        int* h2 = (int*)smem;                          // 1024 ints
        int* gb = (int*)(smem + 4096);                 // 784
        int* hc = (int*)(smem + 7232);                 // 784
        unsigned* lout = (unsigned*)(smem + 10368);    // 3072
        unsigned short* lbv = (unsigned short*)(smem + 22656);  // 3072
        int nch = (E + CHUNK - 1) / CHUNK;
        for (int c = bid; c < nch; c += G) {
            int c0 = c * CHUNK;
            int cnt = min(CHUNK, E - c0);
            for (int i = tid; i < 1024; i += 256) h2[i] = 0;
            __syncthreads();
            for (int i = tid; i < cnt; i += 256)
                atomicAdd(&h2[dst[c0 + i] >> 7], 1);
            __syncthreads();
            for (int off = 1; off < 1024; off <<= 1) {  // inclusive scan
                int t0 = tid, t1 = tid + 256, t2 = tid + 512, t3 = tid + 768;
                int a0 = (t0 >= off) ? h2[t0 - off] : 0;
                int a1 = (t1 >= off) ? h2[t1 - off] : 0;
                int a2 = (t2 >= off) ? h2[t2 - off] : 0;
                int a3 = (t3 >= off) ? h2[t3 - off] : 0;
                __syncthreads();
                h2[t0] += a0; h2[t1] += a1; h2[t2] += a2; h2[t3] += a3;
                __syncthreads();
            }
            for (int s2 = tid; s2 < SUB; s2 += 256) {
                int prev = s2 ? h2[s2 - 1] : 0;
                int v = h2[s2] - prev;
                hc[s2] = prev;
                if (v > 0) gb[s2] = atomicAdd(&cnt2[s2], v);
            }
            __syncthreads();
            for (int i = tid; i < cnt; i += 256) {
                int d = dst[c0 + i];
                int s = src[c0 + i];
                int sb = d >> 7;
                unsigned packed = (unsigned)s | ((unsigned)(d & 127) << 17);
                int pp = atomicAdd(&hc[sb], 1);
                lout[pp] = packed;
                lbv[pp] = (unsigned short)sb;
            }
            __syncthreads();
            for (int i = tid; i < cnt; i += 256) {
                int sb = lbv[i];
                int hx = sb ? h2[sb - 1] : 0;
                binned[(size_t)sb * CAP2 + gb[sb] + (i - hx)] = lout[i];
            }
            __syncthreads();
        }
    }
    gbar(bar, G);

    // ---- P2: per-sub-bucket csr (in place) + deg/dinv/offs + conversion ----
    {
        int* hist = (int*)smem;                 // 128
        int* lbase = (int*)(smem + 512);        // 128
        int* lcur = (int*)(smem + 1024);        // 128
        float* sdv = (float*)(smem + 1536);     // 128
        unsigned* win = (unsigned*)(smem + 2048);  // 3072
        if (bid < SUB) {
            int s = bid;
            int cnt = cnt2[s];
            unsigned* bb = binned + (size_t)s * CAP2;
            for (int j = tid; j < cnt; j += 256) win[j] = bb[j];
            if (tid < 128) { hist[tid] = 0; lcur[tid] = 0; }
            __syncthreads();
            for (int j = tid; j < cnt; j += 256)
                atomicAdd(&hist[win[j] >> 17], 1);
            __syncthreads();
            if (tid == 0) {
                int acc = 0;
                for (int k = 0; k < 128; k++) { lbase[k] = acc; acc += hist[k]; }
            }
            __syncthreads();
            if (tid < 128) {
                int n = (s << 7) + tid;
                float dn = rsqrtf((float)(hist[tid] + 1));  // +1 = self-loop
                sdv[tid] = dn;
                if (n < N) {
                    deg[n] = hist[tid];
                    dinv[n] = dn;
                    offs[n] = s * CAP2 + lbase[tid];
                }
            }
            __syncthreads();
            for (int j = tid; j < cnt; j += 256) {
                unsigned e = win[j];
                int ld = e >> 17;
                bb[lbase[ld] + atomicAdd(&lcur[ld], 1)] = e & 0x1FFFFu;
            }
            int base = s << 11;  // s*128 rows * 16 float4
            const float4* xp = (const float4*)x;
            ushort4* xbp = (ushort4*)xb2;
#pragma unroll
            for (int i2 = 0; i2 < 8; i2++) {
                int idx = tid + 256 * i2;
                int n = (s << 7) + (idx >> 4);
                if (n < N) {
                    float dn = sdv[idx >> 4];
                    float4 v = xp[base + idx];
                    ushort4 b;
                    b.x = f2bf(v.x * dn); b.y = f2bf(v.y * dn);
                    b.z = f2bf(v.z * dn); b.w = f2bf(v.w * dn);
                    xbp[base + idx] = b;
                }
            }
        }
    }
    gbar(bar, 2 * G);

    // ---- P3: agg (16-edge/8-gather) + in-register o=row@W + BN stats ----
    float* Wl = (float*)smem;                // 4096 f32 = 16KB
    float* red = (float*)(smem + 16384);     // 512 f32
    float* ssl = (float*)(smem + 18432);     // 128 f32
    for (int i = tid; i < 4096; i += 256) Wl[i] = W[i];
    __syncthreads();

    const int lane = tid & 63;
    const int p = lane & 31;   // channel pair (channels 2p, 2p+1)
    const int h = lane >> 5;   // half: which edge of a pair this lane gathers
    const int w = tid >> 6;
    const int wvid = (bid * 256 + tid) >> 6;
    const int nw = G * 4;
    const unsigned* xw = (const unsigned*)xb2;
    const int* csr = (const int*)binned;

    float psum = 0.f, psq = 0.f;
    for (int n = wvid; n < N; n += nw) {
        float dn = dinv[n];
        unsigned sv = xw[(size_t)n * 32 + p];  // pre-scaled self row
        float accx = (h == 0) ? bf2f(sv & 0xFFFFu) : 0.f;
        float accy = (h == 0) ? bf2f(sv >> 16) : 0.f;
        int j0 = offs[n];
        int j1 = j0 + deg[n];
        for (int jb = j0; jb < j1; jb += 64) {
            int cnt = min(64, j1 - jb);
            int idx = N;  // zero row for overshoot lanes
            if (lane < cnt) idx = csr[jb + lane];
            for (int j = 0; j < cnt; j += 16) {
                int s0 = __shfl(idx, j + 0 + h),  s1 = __shfl(idx, j + 2 + h);
                int s2 = __shfl(idx, j + 4 + h),  s3 = __shfl(idx, j + 6 + h);
                int s4 = __shfl(idx, j + 8 + h),  s5 = __shfl(idx, j + 10 + h);
                int s6 = __shfl(idx, j + 12 + h), s7 = __shfl(idx, j + 14 + h);
                unsigned v0 = xw[(size_t)s0 * 32 + p];
                unsigned v1 = xw[(size_t)s1 * 32 + p];
                unsigned v2 = xw[(size_t)s2 * 32 + p];
                unsigned v3 = xw[(size_t)s3 * 32 + p];
                unsigned v4 = xw[(size_t)s4 * 32 + p];
                unsigned v5 = xw[(size_t)s5 * 32 + p];
                unsigned v6 = xw[(size_t)s6 * 32 + p];
                unsigned v7 = xw[(size_t)s7 * 32 + p];
                accx += bf2f(v0 & 0xFFFFu); accy += bf2f(v0 >> 16);
                accx += bf2f(v1 & 0xFFFFu); accy += bf2f(v1 >> 16);
                accx += bf2f(v2 & 0xFFFFu); accy += bf2f(v2 >> 16);
                accx += bf2f(v3 & 0xFFFFu); accy += bf2f(v3 >> 16);
                accx += bf2f(v4 & 0xFFFFu); accy += bf2f(v4 >> 16);
                accx += bf2f(v5 & 0xFFFFu); accy += bf2f(v5 >> 16);
                accx += bf2f(v6 & 0xFFFFu); accy += bf2f(v6 >> 16);
                accx += bf2f(v7 & 0xFFFFu); accy += bf2f(v7 >> 16);
            }
        }
        accx += __shfl_xor(accx, 32);
        accy += __shfl_xor(accy, 32);
        // identical on both halves after the xor reduce
        unsigned o32 = (unsigned)f2bf(accx * dn) | ((unsigned)f2bf(accy * dn) << 16);
        if (h == 0) aggb32[(size_t)n * 32 + p] = o32;
        // fused o = row@W via shfl broadcast (fills agg's idle VALU)
        float o = 0.f;
#pragma unroll
        for (int kp = 0; kp < 32; kp++) {
            unsigned u = __shfl(o32, kp);
            o = fmaf(bf2f(u & 0xFFFFu), Wl[(2 * kp) * 64 + lane], o);
            o = fmaf(bf2f(u >> 16), Wl[(2 * kp + 1) * 64 + lane], o);
        }
        psum += o;
        psq = fmaf(o, o, psq);
    }
    red[w * 64 + lane] = psum;
    red[256 + w * 64 + lane] = psq;
    __syncthreads();
    if (w == 0) {
        atomicAdd(&stats[lane],
                  red[lane] + red[64 + lane] + red[128 + lane] + red[192 + lane]);
    } else if (w == 1) {
        atomicAdd(&stats[64 + lane],
                  red[256 + lane] + red[320 + lane] + red[384 + lane] + red[448 + lane]);
    }
    gbar(bar, 3 * G);

    // ---- P4: bnprep + o recompute from own rows (own-L2) + BN+ReLU store ----
    if (tid < 64) {
        float mean = stats[tid] * invN;
        float var = stats[64 + tid] * invN - mean * mean;  // biased var
        float sc = gamma[tid] * rsqrtf(var + BN_EPS);
        ssl[tid] = sc;
        ssl[64 + tid] = beta[tid] - mean * sc;
    }
    __syncthreads();
    float sc = ssl[lane], sh = ssl[64 + lane];
    for (int n = wvid; n < N; n += nw) {
        unsigned v = aggb32[(size_t)n * 32 + p];  // this wave wrote these rows
        float o = 0.f;
#pragma unroll
        for (int kp = 0; kp < 32; kp++) {
            unsigned u = __shfl(v, kp);
            o = fmaf(bf2f(u & 0xFFFFu), Wl[(2 * kp) * 64 + lane], o);
            o = fmaf(bf2f(u >> 16), Wl[(2 * kp + 1) * 64 + lane], o);
        }
        out[(size_t)n * 64 + lane] = fmaxf(fmaf(o, sc, sh), 0.f);
    }
}

extern "C" void kernel_launch(void* const* d_in, const int* in_sizes, int n_in,
                              void* d_out, int out_size, void* d_ws, size_t ws_size,
                              hipStream_t stream) {
    const float* x = (const float*)d_in[0];
    const int* ei = (const int*)d_in[1];
    const float* W = (const float*)d_in[2];
    // d_in[3] = bias: cancels inside BatchNorm, unused.
    const float* gamma = (const float*)d_in[4];
    const float* beta = (const float*)d_in[5];
    float* out = (float*)d_out;

    const int N = in_sizes[0] / 64;
    const int E = in_sizes[1] / 2;
    const int* src = ei;
    const int* dst = ei + E;
    const int SUB = (N + 127) >> 7;  // 782 sub-buckets of 128 nodes
    // Per-sub-bucket count ~ Binomial(E, 128/N): mean 2048, sigma 45.
    // CAP2=3072 = mean + 22.6 sigma -> overflow impossible.

    char* ws = (char*)d_ws;
    size_t o = 0;
    int* bar = (int*)(ws + o); o += 64;            // barrier counter
    int* cnt2 = (int*)(ws + o); o += 4096;         // SUB ints
    float* stats = (float*)(ws + o); o += 512;     // zeroed in P0
    int* deg = (int*)(ws + o); o += (size_t)4 * N;
    int* offs = (int*)(ws + o); o += (size_t)4 * N;
    float* dinv = (float*)(ws + o); o += (size_t)4 * N;
    unsigned short* xb2 = (unsigned short*)(ws + o); o += (size_t)128 * (N + 1);
    unsigned* aggb32 = (unsigned*)(ws + o); o += (size_t)128 * N;
    unsigned* binned = (unsigned*)(ws + o); o += (size_t)4 * SUB * CAP2;
    // csr aliases binned: P2 scatters in place (window staged in LDS).

    hipMemsetAsync(ws, 0, 4160, stream);  // bar + cnt2

    k_mega<<<1280, 256, 0, stream>>>(src, dst, x, W, gamma, beta, out,
                                     bar, cnt2, stats, deg, dinv, offs, xb2,
                                     aggb32, binned, N, E, SUB,
                                     1.0f / (float)N);
}

// Round 6
// 275.756 us; speedup vs baseline: 3.5721x; 3.5721x over previous
//
#include <hip/hip_runtime.h>
#include <hip/hip_bf16.h>

#ifndef BN_EPS
#define BN_EPS 1e-5f
#endif

// ---------------------------------------------------------------------------
// N=100000, C=64, E=1600000.
// R17: R15 pipeline (proven 223.4us) + BN-stats GEMM fused into k_agg.
//   R16 post-mortem: persistent kernel + spin barriers = 4x regression
//   (ACQUIRE-poll -> per-iteration cache invalidate storm; VALUBusy 8%).
//   Reverted. Salvaged piece: k_agg computes o=row@W in-register via shfl
//   broadcast (W staged in LDS, 2-way-free reads) and accumulates BN
//   psum/psq -> k_gemm1 dispatch deleted. k_agg has 68% idle VALU to
//   absorb it; +18KB LDS keeps 8 blocks/CU (wave-limited).
// 5 dispatches: memset(cnt2), pre(direct bin), csr(+conv), agg(+stats),
// gemm2. bias cancels inside BatchNorm, skipped.
// ---------------------------------------------------------------------------

#define CAP2 3072  // per-sub-bucket slack capacity (mean 2049, sigma 45)

__device__ __forceinline__ unsigned short f2bf(float f) {
    unsigned u = __float_as_uint(f);
    u += 0x7FFF + ((u >> 16) & 1);  // round-to-nearest-even
    return (unsigned short)(u >> 16);
}
__device__ __forceinline__ float bf2f(unsigned v) {
    return __uint_as_float(v << 16);
}

// Direct 782-bucket binning: per-block LDS histogram -> in-LDS scan (for
// block-local grouping) -> one global atomicAdd per nonempty bucket to
// reserve space -> grouped flush. Edge format: src | (d&127)<<17 (24 bits).
// Block 0 also zeroes stats[128] and the xb2 zero row.
__global__ __launch_bounds__(256) void k_pre(const int* __restrict__ src,
                                             const int* __restrict__ dst,
                                             int* __restrict__ cnt2,
                                             unsigned* __restrict__ binned,
                                             float* __restrict__ stats,
                                             unsigned* __restrict__ xbz,
                                             int E, int SUB) {
    __shared__ int h2[1024];        // counts -> inclusive scan
    __shared__ int gbase[784];      // global base per sub-bucket
    __shared__ int hcur[784];       // local cursor (starts at local excl)
    __shared__ unsigned lout[4096];
    __shared__ unsigned short lb[4096];
    int tid = threadIdx.x;
    if (blockIdx.x == 0) {
        if (tid < 128) stats[tid] = 0.f;
        if (tid < 32) xbz[tid] = 0u;
    }
    int c0 = blockIdx.x * 4096;
    if (c0 >= E) return;
    int cnt = min(4096, E - c0);
    for (int i = tid; i < 1024; i += 256) h2[i] = 0;
    __syncthreads();
    for (int i = tid; i < cnt; i += 256)
        atomicAdd(&h2[dst[c0 + i] >> 7], 1);
    __syncthreads();
    // inclusive scan of h2[0..1024) with 256 threads (read-all/write-all)
    for (int off = 1; off < 1024; off <<= 1) {
        int t0 = tid, t1 = tid + 256, t2 = tid + 512, t3 = tid + 768;
        int a0 = (t0 >= off) ? h2[t0 - off] : 0;
        int a1 = (t1 >= off) ? h2[t1 - off] : 0;
        int a2 = (t2 >= off) ? h2[t2 - off] : 0;
        int a3 = (t3 >= off) ? h2[t3 - off] : 0;
        __syncthreads();
        h2[t0] += a0; h2[t1] += a1; h2[t2] += a2; h2[t3] += a3;
        __syncthreads();
    }
    // reserve global space per nonempty sub-bucket; init local cursors
    for (int s2 = tid; s2 < SUB; s2 += 256) {
        int prev = s2 ? h2[s2 - 1] : 0;
        int v = h2[s2] - prev;
        hcur[s2] = prev;
        if (v > 0) gbase[s2] = atomicAdd(&cnt2[s2], v);
    }
    __syncthreads();
    // pack into LDS grouped by sub-bucket
    for (int i = tid; i < cnt; i += 256) {
        int d = dst[c0 + i];
        int s = src[c0 + i];
        int sb = d >> 7;
        unsigned packed = (unsigned)s | ((unsigned)(d & 127) << 17);
        int p = atomicAdd(&hcur[sb], 1);
        lout[p] = packed;
        lb[p] = (unsigned short)sb;
    }
    __syncthreads();
    // grouped flush: run for sub-bucket sb sits at [excl, excl+v) in lout
    for (int i = tid; i < cnt; i += 256) {
        int sb = lb[i];
        int hx = sb ? h2[sb - 1] : 0;  // local exclusive base
        binned[(size_t)sb * CAP2 + gbase[sb] + (i - hx)] = lout[i];
    }
}

// One block per 128-node sub-bucket: stage window in LDS, LDS histogram ->
// deg/dinv/offs, scatter csr IN PLACE over the binned region (node-ordered),
// then convert this block's 128 rows: xb2[n] = bf16(dinv[n]*x[n]).
__global__ __launch_bounds__(256) void k_csr(const int* __restrict__ cnt2,
                                             const float* __restrict__ x,
                                             unsigned* __restrict__ binned,
                                             int* __restrict__ deg,
                                             float* __restrict__ dinv,
                                             int* __restrict__ offs,
                                             unsigned short* __restrict__ xb2,
                                             int N) {
    __shared__ int hist[128], lbase[128], lcur[128];
    __shared__ float sdinv[128];
    __shared__ unsigned win[CAP2];
    int s = blockIdx.x;
    int tid = threadIdx.x;
    int cnt = cnt2[s];
    unsigned* bb = binned + (size_t)s * CAP2;
    for (int j = tid; j < cnt; j += 256) win[j] = bb[j];
    if (tid < 128) { hist[tid] = 0; lcur[tid] = 0; }
    __syncthreads();
    for (int j = tid; j < cnt; j += 256)
        atomicAdd(&hist[win[j] >> 17], 1);
    __syncthreads();
    if (tid == 0) {
        int acc = 0;
        for (int k = 0; k < 128; k++) { lbase[k] = acc; acc += hist[k]; }
    }
    __syncthreads();
    if (tid < 128) {  // deg / dinv / offs for this sub-bucket's 128 nodes
        int n = (s << 7) + tid;
        float dn = rsqrtf((float)(hist[tid] + 1));  // +1 = self-loop
        sdinv[tid] = dn;
        if (n < N) {
            deg[n] = hist[tid];
            dinv[n] = dn;
            offs[n] = s * CAP2 + lbase[tid];
        }
    }
    __syncthreads();
    // in-place scatter: reads fully staged in win, writes node-ordered
    for (int j = tid; j < cnt; j += 256) {
        unsigned e = win[j];
        int ld = e >> 17;
        bb[lbase[ld] + atomicAdd(&lcur[ld], 1)] = e & 0x1FFFFu;
    }
    // convert this block's 128 rows (streaming 32KB read, 16KB write)
    int base = s << 11;  // s*128 nodes * 16 float4/row
    const float4* xp = (const float4*)x;
    ushort4* xbp = (ushort4*)xb2;
#pragma unroll
    for (int i = 0; i < 8; i++) {
        int idx = tid + 256 * i;
        int n = (s << 7) + (idx >> 4);
        if (n < N) {
            float dn = sdinv[idx >> 4];
            float4 v = xp[base + idx];
            ushort4 b;
            b.x = f2bf(v.x * dn); b.y = f2bf(v.y * dn);
            b.z = f2bf(v.z * dn); b.w = f2bf(v.w * dn);
            xbp[base + idx] = b;
        }
    }
}

// Wave per node. lane = (half h, channel-pair p): one 4B load = 2 channels of
// one of 2 edges. 16-edge groups, 8 gathers in flight. Rows pre-scaled by
// dinv[src] -> plain adds. Lanes >= cnt hold idx=N (zero row, L1-hot).
// Fused BN-stats: after the row is finished, o = row@W via 32 shfl
// broadcasts against W in LDS (2-way-free reads); psum/psq per lane
// (= channel), LDS-reduced across the block's 4 waves, 128 atomics/block.
__global__ __launch_bounds__(256) void k_agg(const int* __restrict__ offs,
                                             const int* __restrict__ deg,
                                             const int* __restrict__ csr,
                                             const unsigned short* __restrict__ xb2,
                                             const float* __restrict__ dinv,
                                             const float* __restrict__ W,
                                             unsigned* __restrict__ aggb32,
                                             float* __restrict__ stats, int N) {
    __shared__ float Wl[4096];
    __shared__ float red[512];  // [2][4][64]
    int tid = threadIdx.x;
    int lane = tid & 63;
    int p = lane & 31;   // channel pair (channels 2p, 2p+1)
    int h = lane >> 5;   // half: which edge of a pair this lane gathers
    int w = tid >> 6;
    int wid = (blockIdx.x * 256 + tid) >> 6;
    int nw = (gridDim.x * 256) >> 6;
    const unsigned* xw = (const unsigned*)xb2;
    for (int i = tid; i < 4096; i += 256) Wl[i] = W[i];
    __syncthreads();

    float psum = 0.f, psq = 0.f;
    for (int n = wid; n < N; n += nw) {
        float dn = dinv[n];
        unsigned sv = xw[(size_t)n * 32 + p];  // pre-scaled self row
        float accx = (h == 0) ? bf2f(sv & 0xFFFFu) : 0.f;
        float accy = (h == 0) ? bf2f(sv >> 16) : 0.f;
        int j0 = offs[n];
        int j1 = j0 + deg[n];
        for (int jb = j0; jb < j1; jb += 64) {
            int cnt = min(64, j1 - jb);
            int idx = N;  // zero row for overshoot lanes
            if (lane < cnt) idx = csr[jb + lane];
            for (int j = 0; j < cnt; j += 16) {
                int s0 = __shfl(idx, j + 0 + h),  s1 = __shfl(idx, j + 2 + h);
                int s2 = __shfl(idx, j + 4 + h),  s3 = __shfl(idx, j + 6 + h);
                int s4 = __shfl(idx, j + 8 + h),  s5 = __shfl(idx, j + 10 + h);
                int s6 = __shfl(idx, j + 12 + h), s7 = __shfl(idx, j + 14 + h);
                unsigned v0 = xw[(size_t)s0 * 32 + p];
                unsigned v1 = xw[(size_t)s1 * 32 + p];
                unsigned v2 = xw[(size_t)s2 * 32 + p];
                unsigned v3 = xw[(size_t)s3 * 32 + p];
                unsigned v4 = xw[(size_t)s4 * 32 + p];
                unsigned v5 = xw[(size_t)s5 * 32 + p];
                unsigned v6 = xw[(size_t)s6 * 32 + p];
                unsigned v7 = xw[(size_t)s7 * 32 + p];
                accx += bf2f(v0 & 0xFFFFu); accy += bf2f(v0 >> 16);
                accx += bf2f(v1 & 0xFFFFu); accy += bf2f(v1 >> 16);
                accx += bf2f(v2 & 0xFFFFu); accy += bf2f(v2 >> 16);
                accx += bf2f(v3 & 0xFFFFu); accy += bf2f(v3 >> 16);
                accx += bf2f(v4 & 0xFFFFu); accy += bf2f(v4 >> 16);
                accx += bf2f(v5 & 0xFFFFu); accy += bf2f(v5 >> 16);
                accx += bf2f(v6 & 0xFFFFu); accy += bf2f(v6 >> 16);
                accx += bf2f(v7 & 0xFFFFu); accy += bf2f(v7 >> 16);
            }
        }
        accx += __shfl_xor(accx, 32);
        accy += __shfl_xor(accy, 32);
        // both halves hold the full sums after the xor reduce
        unsigned o32 = (unsigned)f2bf(accx * dn) | ((unsigned)f2bf(accy * dn) << 16);
        if (h == 0) aggb32[(size_t)n * 32 + p] = o32;
        // fused o = row@W (lane = output channel); fills idle VALU slots
        float o = 0.f;
#pragma unroll
        for (int kp = 0; kp < 32; kp++) {
            unsigned u = __shfl(o32, kp);  // lane kp holds channels 2kp,2kp+1
            o = fmaf(bf2f(u & 0xFFFFu), Wl[(2 * kp) * 64 + lane], o);
            o = fmaf(bf2f(u >> 16), Wl[(2 * kp + 1) * 64 + lane], o);
        }
        psum += o;
        psq = fmaf(o, o, psq);
    }
    red[w * 64 + lane] = psum;
    red[256 + w * 64 + lane] = psq;
    __syncthreads();
    if (w == 0) {
        atomicAdd(&stats[lane],
                  red[lane] + red[64 + lane] + red[128 + lane] + red[192 + lane]);
    } else if (w == 1) {
        atomicAdd(&stats[64 + lane],
                  red[256 + lane] + red[320 + lane] + red[384 + lane] + red[448 + lane]);
    }
}

// out = BN(agg@W)+ReLU, BN scale/shift derived in-prologue from stats.
__global__ __launch_bounds__(256) void k_gemm2(const unsigned* __restrict__ aggb32,
                                               const float* __restrict__ W,
                                               const float* __restrict__ stats,
                                               const float* __restrict__ gamma,
                                               const float* __restrict__ beta,
                                               float* __restrict__ out, int N,
                                               float invN) {
    __shared__ unsigned tile[256 * 32];
    __shared__ float ssl[128];
    int t = threadIdx.x;
    int lane = t & 63;
    int w = t >> 6;
    int r0 = blockIdx.x * 256;
    const uint4* gp = (const uint4*)(aggb32 + (size_t)r0 * 32);
#pragma unroll
    for (int i = 0; i < 8; i++) {
        int idx = t + 256 * i;
        int n = r0 + (idx >> 3);
        uint4 v = {0u, 0u, 0u, 0u};
        if (n < N) v = gp[idx];
        *(uint4*)(tile + idx * 4) = v;
    }
    if (t < 64) {  // bnprep folded in (redundant per block, trivial)
        float mean = stats[t] * invN;
        float var = stats[64 + t] * invN - mean * mean;  // biased var
        float sc = gamma[t] * rsqrtf(var + BN_EPS);
        ssl[t] = sc;
        ssl[64 + t] = beta[t] - mean * sc;
    }
    float wcol[64];
#pragma unroll
    for (int k = 0; k < 64; k++) wcol[k] = W[k * 64 + lane];
    __syncthreads();
    float sc = ssl[lane], sh = ssl[64 + lane];

    for (int rr = 0; rr < 64; rr += 2) {
        int lr0 = w * 64 + rr;
        int n0 = r0 + lr0;
        if (n0 >= N) break;
        const unsigned* row0 = tile + lr0 * 32;
        const unsigned* row1 = row0 + 32;
        float o0 = 0.f, o1 = 0.f;
#pragma unroll
        for (int kp = 0; kp < 32; kp++) {
            unsigned u0 = row0[kp], u1 = row1[kp];
            o0 = fmaf(bf2f(u0 & 0xFFFFu), wcol[2 * kp], o0);
            o0 = fmaf(bf2f(u0 >> 16), wcol[2 * kp + 1], o0);
            o1 = fmaf(bf2f(u1 & 0xFFFFu), wcol[2 * kp], o1);
            o1 = fmaf(bf2f(u1 >> 16), wcol[2 * kp + 1], o1);
        }
        o0 = fmaxf(fmaf(o0, sc, sh), 0.f);
        o1 = fmaxf(fmaf(o1, sc, sh), 0.f);
        out[(size_t)n0 * 64 + lane] = o0;
        if (n0 + 1 < N) out[(size_t)(n0 + 1) * 64 + lane] = o1;
    }
}

extern "C" void kernel_launch(void* const* d_in, const int* in_sizes, int n_in,
                              void* d_out, int out_size, void* d_ws, size_t ws_size,
                              hipStream_t stream) {
    const float* x = (const float*)d_in[0];
    const int* ei = (const int*)d_in[1];
    const float* W = (const float*)d_in[2];
    // d_in[3] = bias: cancels inside BatchNorm, unused.
    const float* gamma = (const float*)d_in[4];
    const float* beta = (const float*)d_in[5];
    float* out = (float*)d_out;

    const int N = in_sizes[0] / 64;
    const int E = in_sizes[1] / 2;
    const int* src = ei;
    const int* dst = ei + E;
    const int NB = (N + 255) / 256;        // 391
    const int SUB = (N + 127) >> 7;        // 782 sub-buckets of 128 nodes
    // Per-sub-bucket count ~ Binomial(E, 128/N): mean 2049, sigma 45.
    // CAP2=3072 = mean + 22.6 sigma -> overflow impossible.

    char* ws = (char*)d_ws;
    size_t o = 0;
    float* stats = (float*)(ws + o); o += 512;     // zeroed in k_pre block 0
    int* cnt2 = (int*)(ws + o); o += 4096;         // SUB ints, zeroed by memset
    int* deg = (int*)(ws + o); o += (size_t)4 * N;
    int* offs = (int*)(ws + o); o += (size_t)4 * N;
    float* dinv = (float*)(ws + o); o += (size_t)4 * N;
    unsigned short* xb2 = (unsigned short*)(ws + o); o += (size_t)128 * (N + 1);
    unsigned* aggb32 = (unsigned*)(ws + o); o += (size_t)128 * N;
    unsigned* binned = (unsigned*)(ws + o); o += (size_t)4 * SUB * CAP2;
    // csr aliases binned: k_csr scatters in place (window staged in LDS).

    hipMemsetAsync(cnt2, 0, 4096, stream);

    const int EB = (E + 4095) / 4096;      // 391 binning blocks
    k_pre<<<EB, 256, 0, stream>>>(src, dst, cnt2, binned, stats,
                                  (unsigned*)(xb2 + (size_t)N * 64), E, SUB);
    k_csr<<<SUB, 256, 0, stream>>>(cnt2, x, binned, deg, dinv, offs, xb2, N);
    k_agg<<<2048, 256, 0, stream>>>(offs, deg, (const int*)binned, xb2, dinv,
                                    W, aggb32, stats, N);
    k_gemm2<<<NB, 256, 0, stream>>>(aggb32, W, stats, gamma, beta, out, N,
                                    1.0f / (float)N);
}